// Round 15
// baseline (82.764 us; speedup 1.0000x reference)
//
#include <hip/hip_runtime.h>

#define T_LEN   131072
#define NSTEPS  (T_LEN - 2)      // 131070 scan steps (measurements 2..T-1)
#define CHUNK   16
#define NCHUNK  8192             // 8192*16 = 131072 >= NSTEPS
#define NCJ     (NCHUNK * 6)     // 49152 (chunk,coord) lanes
#define CAP     512
#define CPB     64               // chunks per block
#define NBLK    (NCHUNK / CPB)   // 128 blocks
#define K2T     (CPB * 6)        // 384 threads
#define BLK_E   (CPB * CHUNK * 6)// 6144 output elements per block per array
#define LDS_E   (BLK_E + CPB)    // skewed LDS size (6208)

// workspace byte offsets (16B aligned)
#define OFF_STEADY 16
#define OFF_K1     32
#define OFF_K2     (OFF_K1 + CAP * 4)            // 2080
#define OFF_LP     (OFF_K2 + CAP * 4)            // 4128; NCHUNK*16 floats (512KB)
#define OFF_BT     (OFF_LP + NCHUNK * 16 * 4)    // NBLK*16 floats
#define OFF_BI     (OFF_BT + NBLK * 16 * 4)

// Riccati recursion (scalar block form); returns #stored gains, fills table.
__device__ __forceinline__ int riccati(const float* pnc, const float* mnc,
                                       const float* cov, float* g1t, float* g2t,
                                       float& k1o, float& k2o) {
    float q = pnc[0], r = mnc[0];
    float a = cov[0], b = cov[6], c = cov[6 * 12 + 6];
    float pk1 = -1e30f, pk2 = -1e30f, k1 = 0.f, k2 = 0.f;
    int stable = 0, s;
    for (s = 0; s < CAP; ++s) {
        float bp = 2.0f * a - b;
        float t2 = 2.0f * b - c;
        float ap = 2.0f * bp - t2 + q;
        float cp = a;
        float S  = ap + r;
        float invS = 1.0f / S;
        k1 = ap * invS;
        k2 = bp * invS;
        g1t[s] = k1;
        g2t[s] = k2;
        float om = 1.0f - k1;
        a = om * ap;
        b = om * bp;
        c = cp - k2 * bp;
        if (fabsf(k1 - pk1) <= 5e-7f * fabsf(k1) &&
            fabsf(k2 - pk2) <= 5e-7f * (fabsf(k2) + 1e-20f)) {
            if (++stable >= 8) { ++s; break; }
        } else {
            stable = 0;
        }
        pk1 = k1; pk2 = k2;
    }
    k1o = k1; k2o = k2;
    return s;
}

// K1: per-block redundant Riccati (thread 0 -> LDS) + chunk composition +
// intra-block Hillis-Steele scan. Block 0 publishes gains to ws for k_emit.
__global__ __launch_bounds__(K2T) void k_chunk_scan(
    const float* __restrict__ meas, const float* __restrict__ pnc,
    const float* __restrict__ mnc, const float* __restrict__ cov,
    float* __restrict__ ws_f, int* __restrict__ ws_i,
    float* __restrict__ lp, float* __restrict__ btot) {
    __shared__ float g1t[CAP], g2t[CAP];     // 4KB gain table
    __shared__ float lm[CPB][5];             // 2x2 M per chunk (pad 5)
    __shared__ float lu[CPB][13];            // u0[6],u1[6] per chunk (pad 13)
    __shared__ int   s_sc;
    __shared__ float s_k1, s_k2;
    int tid = threadIdx.x;
    int cl = tid / 6;               // chunk-in-block 0..63
    int j  = tid - 6 * cl;          // coord 0..5
    int b  = blockIdx.x;
    if (tid == 0) {
        float k1, k2;
        int sc = riccati(pnc, mnc, cov, g1t, g2t, k1, k2);
        s_sc = sc; s_k1 = k1; s_k2 = k2;
    }
    __syncthreads();
    int sc = s_sc;
    float k1s = s_k1, k2s = s_k2;
    if (b == 0) {
        for (int t = tid; t < sc; t += K2T) {
            ws_f[OFF_K1 / 4 + t] = g1t[t];
            ws_f[OFF_K2 / 4 + t] = g2t[t];
        }
        if (tid == 0) {
            ws_i[0] = sc;
            ws_f[OFF_STEADY / 4]     = k1s;
            ws_f[OFF_STEADY / 4 + 1] = k2s;
        }
    }
    // phase 1: chunk composition. Blocks b>0 have s >= 1024 > sc -> steady.
    int c = b * CPB + cl;
    int s0 = c * CHUNK;
    float m00 = 1.f, m01 = 0.f, m10 = 0.f, m11 = 1.f;
    float u0 = 0.f, u1 = 0.f;
#pragma unroll
    for (int i = 0; i < CHUNK; ++i) {
        int s = s0 + i;
        if (s < NSTEPS) {
            float g1, g2;
            if (b == 0) {
                int si = (s < sc) ? s : 0;
                float ta = g1t[si], tb = g2t[si];
                g1 = (s < sc) ? ta : k1s;
                g2 = (s < sc) ? tb : k2s;
            } else {
                g1 = k1s; g2 = k2s;
            }
            float om  = 1.0f - g1;
            float a00 = 2.0f * om, a01 = -om;
            float a10 = 1.0f - 2.0f * g2, a11 = g2;
            float n00 = a00 * m00 + a01 * m10;
            float n01 = a00 * m01 + a01 * m11;
            float n10 = a10 * m00 + a11 * m10;
            float n11 = a10 * m01 + a11 * m11;
            m00 = n00; m01 = n01; m10 = n10; m11 = n11;
            float mj = meas[(s + 2) * 6 + j];
            float v0 = a00 * u0 + a01 * u1 + g1 * mj;
            float v1 = a10 * u0 + a11 * u1 + g2 * mj;
            u0 = v0; u1 = v1;
        }
    }
    if (j == 0) { lm[cl][0] = m00; lm[cl][1] = m01; lm[cl][2] = m10; lm[cl][3] = m11; }
    lu[cl][j] = u0; lu[cl][6 + j] = u1;
    __syncthreads();
    // phase 2: Hillis-Steele over CPB elements
    for (int off = 1; off < CPB; off <<= 1) {
        bool act = (cl >= off);
        float M0, M1, M2, M3, P0, P1, P2, P3, pu0, pu1;
        if (act) {
            M0 = lm[cl][0]; M1 = lm[cl][1]; M2 = lm[cl][2]; M3 = lm[cl][3];
            P0 = lm[cl - off][0]; P1 = lm[cl - off][1];
            P2 = lm[cl - off][2]; P3 = lm[cl - off][3];
            pu0 = lu[cl - off][j]; pu1 = lu[cl - off][6 + j];
        }
        __syncthreads();
        if (act) {
            float nu0 = M0 * pu0 + M1 * pu1 + u0;
            float nu1 = M2 * pu0 + M3 * pu1 + u1;
            u0 = nu0; u1 = nu1;
            lu[cl][j] = u0; lu[cl][6 + j] = u1;
            if (j == 0) {
                lm[cl][0] = M0 * P0 + M1 * P2; lm[cl][1] = M0 * P1 + M1 * P3;
                lm[cl][2] = M2 * P0 + M3 * P2; lm[cl][3] = M2 * P1 + M3 * P3;
            }
        }
        __syncthreads();
    }
    // phase 3: coalesced write of local prefixes + block total
    for (int w = tid; w < CPB * 16; w += K2T) {
        int cc = w >> 4, k = w & 15;
        float v = (k < 4) ? lm[cc][k] : lu[cc][k - 4];
        lp[(b * CPB + cc) * 16 + k] = v;
    }
    if (tid < 16) {
        float v = (tid < 4) ? lm[CPB - 1][tid] : lu[CPB - 1][tid - 4];
        btot[b * 16 + tid] = v;
    }
}

__device__ __forceinline__ void compose(const float* L, const float* E, float* D) {
    float n00 = L[0] * E[0] + L[1] * E[2];
    float n01 = L[0] * E[1] + L[1] * E[3];
    float n10 = L[2] * E[0] + L[3] * E[2];
    float n11 = L[2] * E[1] + L[3] * E[3];
#pragma unroll
    for (int j = 0; j < 6; ++j) {
        float e0 = E[4 + j], e1 = E[10 + j];
        D[4 + j]  = L[0] * e0 + L[1] * e1 + L[4 + j];
        D[10 + j] = L[2] * e0 + L[3] * e1 + L[10 + j];
    }
    D[0] = n00; D[1] = n01; D[2] = n10; D[3] = n11;
}

// K2: scan over NBLK block totals -> inclusive block prefixes (2 waves).
__global__ __launch_bounds__(NBLK) void k_bscan(const float* __restrict__ btot,
                                                float* __restrict__ binc) {
    __shared__ float ld[NBLK * 16];
    int t = threadIdx.x;
    float S[16];
#pragma unroll
    for (int k = 0; k < 16; ++k) { S[k] = btot[t * 16 + k]; ld[t * 16 + k] = S[k]; }
    __syncthreads();
    for (int off = 1; off < NBLK; off <<= 1) {
        bool act = (t >= off);
        float P[16];
        if (act) {
#pragma unroll
            for (int k = 0; k < 16; ++k) P[k] = ld[(t - off) * 16 + k];
        }
        __syncthreads();
        if (act) {
            float D[16];
            compose(S, P, D);
#pragma unroll
            for (int k = 0; k < 16; ++k) { S[k] = D[k]; ld[t * 16 + k] = S[k]; }
        }
        __syncthreads();
    }
#pragma unroll
    for (int k = 0; k < 16; ++k) binc[t * 16 + k] = S[k];
}

__device__ __forceinline__ void load_gains(int s, int sc, const float* k1a,
                                           const float* k2a, float k1s, float k2s,
                                           float& g1, float& g2) {
    int si = (s < sc) ? s : 0;
    float a = k1a[si], b = k2a[si];
    g1 = (s < sc) ? a : k1s;
    g2 = (s < sc) ? b : k2s;
}

// K3: replay with LDS-staged, fully-coalesced output flush.
// 384 threads = 64 chunks x 6 coords; block outputs are contiguous ranges.
__global__ __launch_bounds__(K2T) void k_emit(
    const float* __restrict__ meas, const float* __restrict__ ws_f,
    const int* __restrict__ ws_i, const float* __restrict__ lp,
    const float* __restrict__ binc, float* __restrict__ out) {
    __shared__ float eld[LDS_E];   // est stage (skew addr = e + e/96), 24.8KB
    __shared__ float pld[LDS_E];   // pred stage, 24.8KB
    int tid = threadIdx.x;
    int b = blockIdx.x;
    int cl = tid / 6;
    int j  = tid - 6 * cl;
    int c  = b * CPB + cl;
    float* est  = out;
    float* pred = out + T_LEN * 6;
    float* vel  = out + T_LEN * 12;
    if (b == 0 && cl == 0) {
        float m0 = meas[j], m1 = meas[6 + j];
        est[j] = m0; est[6 + j] = m1;
        pred[j] = m0; pred[6 + j] = m1;
        vel[j] = m1 - m0;
    }
    // start state: z1 -> block prefix (b-1) -> local prefix (c-1)
    float zx = meas[6 + j], zy = meas[j];
    if (b > 0) {
        const float* B = binc + (b - 1) * 16;
        float nx = B[0] * zx + B[1] * zy + B[4 + j];
        float ny = B[2] * zx + B[3] * zy + B[10 + j];
        zx = nx; zy = ny;
    }
    if (cl > 0) {
        const float* L = lp + (c - 1) * 16;
        float nx = L[0] * zx + L[1] * zy + L[4 + j];
        float ny = L[2] * zx + L[3] * zy + L[10 + j];
        zx = nx; zy = ny;
    }
    float x = zx, y = zy;
    int sc = ws_i[0];
    float k1s = ws_f[OFF_STEADY / 4], k2s = ws_f[OFF_STEADY / 4 + 1];
    const float* k1a = ws_f + OFF_K1 / 4;
    const float* k2a = ws_f + OFF_K2 / 4;
    int s0 = c * CHUNK;
    float v[CHUNK];
#pragma unroll
    for (int i = 0; i < CHUNK; ++i) {
        int s = s0 + i;
        if (s < NSTEPS) {
            float g1, g2;
            load_gains(s, sc, k1a, k2a, k1s, k2s, g1, g2);
            float mj  = meas[(s + 2) * 6 + j];
            float vx  = x - y;
            float p   = x + vx;
            float inn = mj - p;
            float xn  = p + g1 * inn;
            float yn  = x + g2 * inn;
            int lidx = (cl * CHUNK + i) * 6 + j + cl;   // skewed
            eld[lidx] = xn;
            pld[lidx] = p;
            v[i] = xn - yn;
            x = xn; y = yn;
        }
    }
    __syncthreads();
    // flush est/pred: consecutive lanes -> consecutive global floats
    int base = b * BLK_E;
    const int T6 = T_LEN * 6;
#pragma unroll
    for (int k = 0; k < BLK_E / K2T; ++k) {   // 16 iters
        int e = k * K2T + tid;                // 0..6143
        int a = e + e / 96;                   // skewed LDS addr
        int g = base + e + 12;                // est rows start at row 2
        if (g < T6) {
            est[g]  = eld[a];
            pred[g] = pld[a];
        }
    }
    __syncthreads();
    // restage vel from registers (reuse eld)
#pragma unroll
    for (int i = 0; i < CHUNK; ++i) {
        if (s0 + i < NSTEPS) {
            eld[(cl * CHUNK + i) * 6 + j + cl] = v[i];
        }
    }
    __syncthreads();
#pragma unroll
    for (int k = 0; k < BLK_E / K2T; ++k) {
        int e = k * K2T + tid;
        int a = e + e / 96;
        int g = base + e + 6;                 // vel rows start at row 1
        if (g < NSTEPS * 6) {
            vel[g] = eld[a];
        }
    }
}

extern "C" void kernel_launch(void* const* d_in, const int* in_sizes, int n_in,
                              void* d_out, int out_size, void* d_ws, size_t ws_size,
                              hipStream_t stream) {
    const float* meas = (const float*)d_in[0];
    const float* pnc  = (const float*)d_in[1];
    const float* mnc  = (const float*)d_in[2];
    const float* cov  = (const float*)d_in[3];
    float* ws_f = (float*)d_ws;
    int*   ws_i = (int*)d_ws;
    float* lp   = ws_f + OFF_LP / 4;
    float* btot = ws_f + OFF_BT / 4;
    float* binc = ws_f + OFF_BI / 4;
    float* out  = (float*)d_out;

    k_chunk_scan<<<NBLK, K2T, 0, stream>>>(meas, pnc, mnc, cov, ws_f, ws_i, lp, btot);
    k_bscan<<<1, NBLK, 0, stream>>>(btot, binc);
    k_emit<<<NBLK, K2T, 0, stream>>>(meas, ws_f, ws_i, lp, binc, out);
}

// Round 16
// 81.702 us; speedup vs baseline: 1.0130x; 1.0130x over previous
//
#include <hip/hip_runtime.h>

#define T_LEN   131072
#define NSTEPS  (T_LEN - 2)      // 131070 scan steps (measurements 2..T-1)
#define CHUNK   16
#define NCHUNK  8192             // 8192*16 = 131072 >= NSTEPS
#define NCJ     (NCHUNK * 6)     // 49152 (chunk,coord) lanes
#define CAP     512
#define MAXIT   160              // hard cap: gains are ULP-steady long before this
#define CPB     64               // chunks per block
#define NBLK    (NCHUNK / CPB)   // 128 blocks
#define K2T     (CPB * 6)        // 384 threads

// workspace byte offsets (16B aligned)
#define OFF_STEADY 16
#define OFF_K1     32
#define OFF_K2     (OFF_K1 + CAP * 4)            // 2080
#define OFF_LP     (OFF_K2 + CAP * 4)            // 4128; NCHUNK*16 floats (512KB)
#define OFF_BT     (OFF_LP + NCHUNK * 16 * 4)    // NBLK*16 floats
#define OFF_BI     (OFF_BT + NBLK * 16 * 4)

// Riccati recursion (scalar block form); hard-capped at MAXIT iterations.
__device__ __forceinline__ int riccati(const float* pnc, const float* mnc,
                                       const float* cov, float* g1t, float* g2t,
                                       float& k1o, float& k2o) {
    float q = pnc[0], r = mnc[0];
    float a = cov[0], b = cov[6], c = cov[6 * 12 + 6];
    float pk1 = -1e30f, pk2 = -1e30f, k1 = 0.f, k2 = 0.f;
    int stable = 0, s;
    for (s = 0; s < MAXIT; ++s) {
        float bp = 2.0f * a - b;
        float t2 = 2.0f * b - c;
        float ap = 2.0f * bp - t2 + q;
        float cp = a;
        float S  = ap + r;
        float invS = 1.0f / S;
        k1 = ap * invS;
        k2 = bp * invS;
        g1t[s] = k1;
        g2t[s] = k2;
        float om = 1.0f - k1;
        a = om * ap;
        b = om * bp;
        c = cp - k2 * bp;
        if (fabsf(k1 - pk1) <= 5e-7f * fabsf(k1) &&
            fabsf(k2 - pk2) <= 5e-7f * (fabsf(k2) + 1e-20f)) {
            if (++stable >= 8) { ++s; break; }
        } else {
            stable = 0;
        }
        pk1 = k1; pk2 = k2;
    }
    k1o = k1; k2o = k2;
    return s;
}

// K1: per-block redundant Riccati (thread 0 -> LDS) + chunk composition +
// intra-block Hillis-Steele scan. Block 0 publishes gains to ws for k_emit.
__global__ __launch_bounds__(K2T) void k_chunk_scan(
    const float* __restrict__ meas, const float* __restrict__ pnc,
    const float* __restrict__ mnc, const float* __restrict__ cov,
    float* __restrict__ ws_f, int* __restrict__ ws_i,
    float* __restrict__ lp, float* __restrict__ btot) {
    __shared__ float g1t[MAXIT], g2t[MAXIT];
    __shared__ float lm[CPB][5];             // 2x2 M per chunk (pad 5)
    __shared__ float lu[CPB][13];            // u0[6],u1[6] per chunk (pad 13)
    __shared__ int   s_sc;
    __shared__ float s_k1, s_k2;
    int tid = threadIdx.x;
    int cl = tid / 6;               // chunk-in-block 0..63
    int j  = tid - 6 * cl;          // coord 0..5
    int b  = blockIdx.x;
    if (tid == 0) {
        float k1, k2;
        int sc = riccati(pnc, mnc, cov, g1t, g2t, k1, k2);
        s_sc = sc; s_k1 = k1; s_k2 = k2;
    }
    __syncthreads();
    int sc = s_sc;
    float k1s = s_k1, k2s = s_k2;
    if (b == 0) {
        for (int t = tid; t < sc; t += K2T) {
            ws_f[OFF_K1 / 4 + t] = g1t[t];
            ws_f[OFF_K2 / 4 + t] = g2t[t];
        }
        if (tid == 0) {
            ws_i[0] = sc;
            ws_f[OFF_STEADY / 4]     = k1s;
            ws_f[OFF_STEADY / 4 + 1] = k2s;
        }
    }
    // phase 1: chunk composition. Blocks b>0 have s >= 1024 > sc -> steady.
    int c = b * CPB + cl;
    int s0 = c * CHUNK;
    float m00 = 1.f, m01 = 0.f, m10 = 0.f, m11 = 1.f;
    float u0 = 0.f, u1 = 0.f;
#pragma unroll
    for (int i = 0; i < CHUNK; ++i) {
        int s = s0 + i;
        if (s < NSTEPS) {
            float g1, g2;
            if (b == 0 && s < sc) { g1 = g1t[s]; g2 = g2t[s]; }
            else                  { g1 = k1s;    g2 = k2s;    }
            float om  = 1.0f - g1;
            float a00 = 2.0f * om, a01 = -om;
            float a10 = 1.0f - 2.0f * g2, a11 = g2;
            float n00 = a00 * m00 + a01 * m10;
            float n01 = a00 * m01 + a01 * m11;
            float n10 = a10 * m00 + a11 * m10;
            float n11 = a10 * m01 + a11 * m11;
            m00 = n00; m01 = n01; m10 = n10; m11 = n11;
            float mj = meas[(s + 2) * 6 + j];
            float v0 = a00 * u0 + a01 * u1 + g1 * mj;
            float v1 = a10 * u0 + a11 * u1 + g2 * mj;
            u0 = v0; u1 = v1;
        }
    }
    if (j == 0) { lm[cl][0] = m00; lm[cl][1] = m01; lm[cl][2] = m10; lm[cl][3] = m11; }
    lu[cl][j] = u0; lu[cl][6 + j] = u1;
    __syncthreads();
    // phase 2: Hillis-Steele over CPB elements
    for (int off = 1; off < CPB; off <<= 1) {
        bool act = (cl >= off);
        float M0, M1, M2, M3, P0, P1, P2, P3, pu0, pu1;
        if (act) {
            M0 = lm[cl][0]; M1 = lm[cl][1]; M2 = lm[cl][2]; M3 = lm[cl][3];
            P0 = lm[cl - off][0]; P1 = lm[cl - off][1];
            P2 = lm[cl - off][2]; P3 = lm[cl - off][3];
            pu0 = lu[cl - off][j]; pu1 = lu[cl - off][6 + j];
        }
        __syncthreads();
        if (act) {
            float nu0 = M0 * pu0 + M1 * pu1 + u0;
            float nu1 = M2 * pu0 + M3 * pu1 + u1;
            u0 = nu0; u1 = nu1;
            lu[cl][j] = u0; lu[cl][6 + j] = u1;
            if (j == 0) {
                lm[cl][0] = M0 * P0 + M1 * P2; lm[cl][1] = M0 * P1 + M1 * P3;
                lm[cl][2] = M2 * P0 + M3 * P2; lm[cl][3] = M2 * P1 + M3 * P3;
            }
        }
        __syncthreads();
    }
    // phase 3: coalesced write of local prefixes + block total
    for (int w = tid; w < CPB * 16; w += K2T) {
        int cc = w >> 4, k = w & 15;
        float v = (k < 4) ? lm[cc][k] : lu[cc][k - 4];
        lp[(b * CPB + cc) * 16 + k] = v;
    }
    if (tid < 16) {
        float v = (tid < 4) ? lm[CPB - 1][tid] : lu[CPB - 1][tid - 4];
        btot[b * 16 + tid] = v;
    }
}

__device__ __forceinline__ void compose(const float* L, const float* E, float* D) {
    float n00 = L[0] * E[0] + L[1] * E[2];
    float n01 = L[0] * E[1] + L[1] * E[3];
    float n10 = L[2] * E[0] + L[3] * E[2];
    float n11 = L[2] * E[1] + L[3] * E[3];
#pragma unroll
    for (int j = 0; j < 6; ++j) {
        float e0 = E[4 + j], e1 = E[10 + j];
        D[4 + j]  = L[0] * e0 + L[1] * e1 + L[4 + j];
        D[10 + j] = L[2] * e0 + L[3] * e1 + L[10 + j];
    }
    D[0] = n00; D[1] = n01; D[2] = n10; D[3] = n11;
}

// K2: scan over NBLK block totals -> inclusive block prefixes (2 waves).
__global__ __launch_bounds__(NBLK) void k_bscan(const float* __restrict__ btot,
                                                float* __restrict__ binc) {
    __shared__ float ld[NBLK * 16];
    int t = threadIdx.x;
    float S[16];
#pragma unroll
    for (int k = 0; k < 16; ++k) { S[k] = btot[t * 16 + k]; ld[t * 16 + k] = S[k]; }
    __syncthreads();
    for (int off = 1; off < NBLK; off <<= 1) {
        bool act = (t >= off);
        float P[16];
        if (act) {
#pragma unroll
            for (int k = 0; k < 16; ++k) P[k] = ld[(t - off) * 16 + k];
        }
        __syncthreads();
        if (act) {
            float D[16];
            compose(S, P, D);
#pragma unroll
            for (int k = 0; k < 16; ++k) { S[k] = D[k]; ld[t * 16 + k] = S[k]; }
        }
        __syncthreads();
    }
#pragma unroll
    for (int k = 0; k < 16; ++k) binc[t * 16 + k] = S[k];
}

// K3: per-(chunk,coord) replay, j-fastest mapping (proven round 14).
__global__ __launch_bounds__(256) void k_emit(
    const float* __restrict__ meas, const float* __restrict__ ws_f,
    const int* __restrict__ ws_i, const float* __restrict__ lp,
    const float* __restrict__ binc, float* __restrict__ out) {
    int g = blockIdx.x * 256 + threadIdx.x;
    if (g >= NCJ) return;
    int c = g / 6;
    int j = g - 6 * c;
    int b = c / CPB, cl = c & (CPB - 1);
    float* est  = out;
    float* pred = out + T_LEN * 6;
    float* vel  = out + T_LEN * 12;
    if (c == 0) {
        float m0 = meas[j], m1 = meas[6 + j];
        est[j] = m0; est[6 + j] = m1;
        pred[j] = m0; pred[6 + j] = m1;
        vel[j] = m1 - m0;
    }
    // z1 then apply block prefix then local prefix
    float zx = meas[6 + j], zy = meas[j];
    if (b > 0) {
        const float* B = binc + (b - 1) * 16;
        float nx = B[0] * zx + B[1] * zy + B[4 + j];
        float ny = B[2] * zx + B[3] * zy + B[10 + j];
        zx = nx; zy = ny;
    }
    if (cl > 0) {
        const float* L = lp + (c - 1) * 16;
        float nx = L[0] * zx + L[1] * zy + L[4 + j];
        float ny = L[2] * zx + L[3] * zy + L[10 + j];
        zx = nx; zy = ny;
    }
    float x = zx, y = zy;
    int sc = ws_i[0];
    float k1s = ws_f[OFF_STEADY / 4], k2s = ws_f[OFF_STEADY / 4 + 1];
    const float* k1a = ws_f + OFF_K1 / 4;
    const float* k2a = ws_f + OFF_K2 / 4;
    int s0 = c * CHUNK;
#pragma unroll
    for (int i = 0; i < CHUNK; ++i) {
        int s = s0 + i;
        if (s < NSTEPS) {
            float g1, g2;
            if (s < sc) { g1 = k1a[s]; g2 = k2a[s]; }
            else        { g1 = k1s;    g2 = k2s;    }
            float mj  = meas[(s + 2) * 6 + j];
            float vx  = x - y;
            float p   = x + vx;
            float inn = mj - p;
            float xn  = p + g1 * inn;
            float yn  = x + g2 * inn;
            est[(s + 2) * 6 + j]  = xn;
            pred[(s + 2) * 6 + j] = p;
            if (s < NSTEPS - 1) vel[(s + 1) * 6 + j] = xn - yn;
            x = xn; y = yn;
        }
    }
}

extern "C" void kernel_launch(void* const* d_in, const int* in_sizes, int n_in,
                              void* d_out, int out_size, void* d_ws, size_t ws_size,
                              hipStream_t stream) {
    const float* meas = (const float*)d_in[0];
    const float* pnc  = (const float*)d_in[1];
    const float* mnc  = (const float*)d_in[2];
    const float* cov  = (const float*)d_in[3];
    float* ws_f = (float*)d_ws;
    int*   ws_i = (int*)d_ws;
    float* lp   = ws_f + OFF_LP / 4;
    float* btot = ws_f + OFF_BT / 4;
    float* binc = ws_f + OFF_BI / 4;
    float* out  = (float*)d_out;

    k_chunk_scan<<<NBLK, K2T, 0, stream>>>(meas, pnc, mnc, cov, ws_f, ws_i, lp, btot);
    k_bscan<<<1, NBLK, 0, stream>>>(btot, binc);
    k_emit<<<NCJ / 256, 256, 0, stream>>>(meas, ws_f, ws_i, lp, binc, out);
}